// Round 2
// baseline (228.871 us; speedup 1.0000x reference)
//
#include <hip/hip_runtime.h>

#define TAGS 256
#define RPW 4   // rows per wave

// One 64-lane wave handles 4 rows of 256 tags, interleaved for MLP/ILP.
// Per row: lane i owns tags [4i,4i+4). float4 load -> local max ->
// value-only 6-step butterfly (interleaved across the 4 rows) ->
// ballot+ffs to recover first-occurrence argmax -> float4 gather of
// transitions[argmax] -> add -> float4 store.
__global__ __launch_bounds__(256) void crf_head_kernel(
    const float* __restrict__ in,
    const float* __restrict__ trans,
    float* __restrict__ out,
    int rows)
{
    int wave = (int)((blockIdx.x * blockDim.x + threadIdx.x) >> 6);
    int lane = threadIdx.x & 63;
    int r0   = wave * RPW;
    if (r0 >= rows) return;

    // ---- 4 independent row loads (issued back-to-back: 4 KB in flight) ----
    float4 v[RPW];
    #pragma unroll
    for (int j = 0; j < RPW; ++j)
        v[j] = ((const float4*)(in + (size_t)(r0 + j) * TAGS))[lane];

    // ---- lane-local max + first-occurrence local index ----
    float lm[RPW];  // lane-local max (kept for the ballot)
    int   li[RPW];  // global tag index of lane-local first max
    float m[RPW];   // running reduction value
    #pragma unroll
    for (int j = 0; j < RPW; ++j) {
        float a = fmaxf(v[j].x, v[j].y);
        float b = fmaxf(v[j].z, v[j].w);
        lm[j] = fmaxf(a, b);
        // first occurrence among the 4 owned tags
        int off = (v[j].x == lm[j]) ? 0 : (v[j].y == lm[j]) ? 1
                : (v[j].z == lm[j]) ? 2 : 3;
        li[j] = lane * 4 + off;
        m[j]  = lm[j];
    }

    // ---- value-only butterfly, 4 rows interleaved (DS latency pipelines) ----
    #pragma unroll
    for (int off = 32; off >= 1; off >>= 1) {
        #pragma unroll
        for (int j = 0; j < RPW; ++j) {
            float om = __shfl_xor(m[j], off, 64);
            m[j] = fmaxf(m[j], om);
        }
    }

    // ---- recover argmax: lowest lane holding the max owns the lowest tags ----
    int mi[RPW];
    #pragma unroll
    for (int j = 0; j < RPW; ++j) {
        unsigned long long mask = __ballot(lm[j] == m[j]);
        int src = __ffsll((long long)mask) - 1;
        mi[j] = __shfl(li[j], src, 64);
    }

    // ---- 4 independent gathers of transitions rows (L2-hot) ----
    float4 t[RPW];
    #pragma unroll
    for (int j = 0; j < RPW; ++j)
        t[j] = ((const float4*)(trans + (size_t)mi[j] * TAGS))[lane];

    // ---- add + store ----
    #pragma unroll
    for (int j = 0; j < RPW; ++j) {
        float4 o;
        o.x = v[j].x + t[j].x;
        o.y = v[j].y + t[j].y;
        o.z = v[j].z + t[j].z;
        o.w = v[j].w + t[j].w;
        ((float4*)(out + (size_t)(r0 + j) * TAGS))[lane] = o;
    }
}

extern "C" void kernel_launch(void* const* d_in, const int* in_sizes, int n_in,
                              void* d_out, int out_size, void* d_ws, size_t ws_size,
                              hipStream_t stream) {
    const float* in    = (const float*)d_in[0];   // [B, T, TAGS] fp32
    const float* trans = (const float*)d_in[1];   // [TAGS, TAGS] fp32
    float* out = (float*)d_out;                   // [B, T, TAGS] fp32

    int rows  = in_sizes[0] / TAGS;               // B*T = 131072 (divisible by RPW)
    int waves = (rows + RPW - 1) / RPW;           // 32768 waves
    int blocks = (waves + 3) / 4;                 // 4 waves (256 threads) per block
    crf_head_kernel<<<dim3(blocks), dim3(256), 0, stream>>>(in, trans, out, rows);
}

// Round 3
// 228.081 us; speedup vs baseline: 1.0035x; 1.0035x over previous
//
#include <hip/hip_runtime.h>

#define TAGS 256

// Persistent kernel: 2048 blocks x 256 threads = 8192 waves = 32 waves/CU on
// 256 CUs. Each wave grid-strides over rows (16 rows/wave at B*T=131072) with
// a 1-deep software pipeline: next row's float4 load is issued before the
// current row's reduce/gather/store consumes its data.
//
// Per row: lane i owns tags [4i,4i+4). Local max -> 6-step value-only
// shfl_xor butterfly -> ballot (first set lane = first-occurrence winner)
// -> readlane (scalar broadcast, no DS op) -> float4 gather of
// transitions[argmax] (L2-hot, 256 KB) -> add -> float4 store.
__global__ __launch_bounds__(256, 8) void crf_head_kernel(
    const float* __restrict__ in,
    const float* __restrict__ trans,
    float* __restrict__ out,
    int rows)
{
    const int wave   = (int)((blockIdx.x * blockDim.x + threadIdx.x) >> 6);
    const int lane   = threadIdx.x & 63;
    const int nwaves = (int)((gridDim.x * blockDim.x) >> 6);

    int r = wave;
    if (r >= rows) return;

    float4 cur = ((const float4*)(in + (size_t)r * TAGS))[lane];

    while (r < rows) {
        const int rn = r + nwaves;          // wave-uniform
        float4 nxt;
        if (rn < rows)                       // uniform branch, no divergence
            nxt = ((const float4*)(in + (size_t)rn * TAGS))[lane];

        // ---- lane-local max + first-occurrence local tag index ----
        const float a  = fmaxf(cur.x, cur.y);
        const float b  = fmaxf(cur.z, cur.w);
        const float lm = fmaxf(a, b);
        const int off  = (cur.x == lm) ? 0 : (cur.y == lm) ? 1
                       : (cur.z == lm) ? 2 : 3;
        const int li   = lane * 4 + off;

        // ---- value-only 64-lane max butterfly (6 DS ops) ----
        float m = lm;
        #pragma unroll
        for (int s = 32; s >= 1; s >>= 1)
            m = fmaxf(m, __shfl_xor(m, s, 64));

        // ---- argmax recovery: lowest lane holding the max (scalar path) ----
        const unsigned long long mask = __ballot(lm == m);
        const int src = __ffsll((long long)mask) - 1;            // uniform
        const int mi  = __builtin_amdgcn_readlane(li, src);      // v_readlane

        // ---- gather transitions[mi] (hot in L2: 256 rows x 1 KB) ----
        const float4 t = ((const float4*)(trans + (size_t)mi * TAGS))[lane];

        float4 o;
        o.x = cur.x + t.x;
        o.y = cur.y + t.y;
        o.z = cur.z + t.z;
        o.w = cur.w + t.w;
        ((float4*)(out + (size_t)r * TAGS))[lane] = o;

        r = rn;
        cur = nxt;
    }
}

extern "C" void kernel_launch(void* const* d_in, const int* in_sizes, int n_in,
                              void* d_out, int out_size, void* d_ws, size_t ws_size,
                              hipStream_t stream) {
    const float* in    = (const float*)d_in[0];   // [B, T, TAGS] fp32
    const float* trans = (const float*)d_in[1];   // [TAGS, TAGS] fp32
    float* out = (float*)d_out;                   // [B, T, TAGS] fp32

    const int rows = in_sizes[0] / TAGS;          // B*T = 131072

    // 256 CUs x 8 blocks/CU (32 waves/CU) = 2048 blocks; grid-stride inside.
    int blocks = 2048;
    const int max_blocks = (rows + 3) / 4;        // never launch idle blocks
    if (blocks > max_blocks) blocks = max_blocks;

    crf_head_kernel<<<dim3(blocks), dim3(256), 0, stream>>>(in, trans, out, rows);
}